// Round 8
// baseline (849.946 us; speedup 1.0000x reference)
//
#include <hip/hip_runtime.h>
#include <hip/hip_bf16.h>
#include <math.h>

typedef __attribute__((ext_vector_type(4))) float f32x4;
typedef __attribute__((ext_vector_type(16))) float f32x16;
typedef __attribute__((ext_vector_type(8))) int i32x8;
typedef __attribute__((ext_vector_type(4))) int i32x4;

#define TEMP_INV 14.2857142857142857f     // 1/0.07
#define SCALE_EPI 0.013950892857142857f   // TEMP_INV / 1024 (32*32 prescale)
#define UNIT_SCALE 0x7f7f7f7f             // E8M0 127 -> x1.0 exact (verified)

union frag32 {
  i32x8 v8;
  struct { i32x4 lo; i32x4 hi; } s;
};

// ---- async global->LDS, 16B per lane
static __device__ inline void async16(const void* g, void* l) {
  __builtin_amdgcn_global_load_lds(
      (const __attribute__((address_space(1))) unsigned int*)g,
      (__attribute__((address_space(3))) unsigned int*)l,
      16, 0, 0);
}

// ---- OCP fp4 e2m1 encode of y (|y| clamped to 6): monotone 3-bit code
// values {0,0.5,1,1.5,2,3,4,6}; round-to-nearest via threshold counts.
static __device__ inline int fp4e(float y) {
  const float af = fabsf(y);
  int code = (af > 0.25f) + (af > 0.75f) + (af > 1.25f) + (af > 1.75f) +
             (af > 2.5f) + (af > 3.5f) + (af > 5.0f);
  return code | (y < 0.f ? 8 : 0);
}

// ============================================================
// Fragment-major MX-fp4 format (R8):
//   panel p = 32 rows, k-step s = 64 K-elems. record(p,s) = 1 KB at
//   (p*16+s)*1024. Lane l holds row p*32+(l&31), k-elems
//   s*64+(l>>5)*32..+31 as 16 B at rec + l*16; k-elem j at byte j>>1,
//   nibble j&1 (low nibble = even j). Values are 32*x (exact pow-2
//   prescale); epilogue divides by 1024. A and B share the identical
//   packing, so any consistent k-permutation cancels in the dot.
// ============================================================

// ============================================================
// Kernel 1: L2-normalize rows (D=1024) -> fp4 fragment-major.
// Block = one 32-row panel (1024 thr = 32 rows x 32 chunks). LDS-pack
// the panel's 16 KB then linear int4 copy-out (R6 pattern, halved).
// ============================================================
__global__ __launch_bounds__(1024) void normalize_rows(
    const float* __restrict__ a, const float* __restrict__ b,
    int* __restrict__ oa, int* __restrict__ ob,
    float* __restrict__ pos_acc, float* __restrict__ neg_acc,
    int N, int D) {
  __shared__ __align__(16) unsigned short sPk[8192];  // 16 KB

  const int blk = blockIdx.x;          // 0..511
  const bool isA = blk < 256;
  const int p = isA ? blk : blk - 256;
  const float* src = (isA ? a : b) + (size_t)p * 32 * D;
  int* out = isA ? oa : ob;

  const int tid = threadIdx.x;
  const int r = tid >> 5;   // row within panel
  const int c = tid & 31;   // chunk within row

  if (isA && c == 0) {
    pos_acc[p * 32 + r] = 0.f;
    neg_acc[p * 32 + r] = 0.f;
  }

  const float4* inr = (const float4*)(src + (size_t)r * D);
  float4 v[8];
#pragma unroll
  for (int i = 0; i < 8; i++) v[i] = inr[c + 32 * i];

  float ss = 0.f;
#pragma unroll
  for (int i = 0; i < 8; i++)
    ss += v[i].x * v[i].x + v[i].y * v[i].y + v[i].z * v[i].z + v[i].w * v[i].w;
#pragma unroll
  for (int m = 16; m >= 1; m >>= 1) ss += __shfl_xor(ss, m, 32);
  const float inv = 32.0f / fmaxf(sqrtf(ss), 1e-12f);  // pre-scale by 32

#pragma unroll
  for (int i = 0; i < 8; i++) {
    const int f = c + 32 * i;  // float4 index; k-base = 4f
    const int n0 = fp4e(v[i].x * inv);
    const int n1 = fp4e(v[i].y * inv);
    const int n2 = fp4e(v[i].z * inv);
    const int n3 = fp4e(v[i].w * inv);
    const unsigned short h =
        (unsigned short)(n0 | (n1 << 4) | (n2 << 8) | (n3 << 12));
    const int s = f >> 4;            // 64-k step
    const int hi = (f >> 3) & 1;     // k-half -> lane group
    sPk[s * 512 + (hi * 32 + r) * 8 + (f & 7)] = h;
  }
  __syncthreads();

  // linear copy-out: 16 KB = 1024 int4, one per thread
  const int4* sp4 = (const int4*)sPk;
  ((int4*)out)[(size_t)p * 1024 + tid] = sp4[tid];
}

// ============================================================
// Kernel 2: fused MX-fp4 MFMA GEMM + exp epilogue.
// R8 = R5's proven 2-barrier skeleton (best structure: 138 us @ fp8)
// with the format halved to fp4: staging 16 KB/K-tile, ONE b128 per
// fragment (upper operand regs zeroed - correct under either 4-reg or
// 8-reg HW reading), MFMA fmt args cbsz=blgp=4. LDS 16 KB total ->
// launch_bounds(256,6) = 6 blocks/CU (more TLP vs R5's 3.2).
// Tile 128x128, 4 waves 2x2, wave 64x64, acc[2][2] 32x32.
// Fragment reads stride-16 -> zero bank conflicts (R5-verified).
// ============================================================
__global__ __launch_bounds__(256, 6) void infonce_gemm(
    const unsigned char* __restrict__ A, const unsigned char* __restrict__ B,
    const int* __restrict__ la, const int* __restrict__ lb,
    float* __restrict__ pos_acc, float* __restrict__ neg_acc) {
  __shared__ __align__(16) unsigned char sA[8192];
  __shared__ __align__(16) unsigned char sB[8192];

  const int tid = threadIdx.x;
  const int lane = tid & 63;
  const int wave = tid >> 6;  // 0..3
  const int wm = wave >> 1;   // 0..1 (M half: 64 rows)
  const int wn = wave & 1;    // 0..1 (N half: 64 cols)

  // grid 4096 = 64 by x 64 bx; bijective XCD rectangle swizzle
  const int bid = blockIdx.x;
  const int xcd = bid & 7;
  const int local = bid >> 3;              // 0..511
  const int by = xcd * 8 + (local & 7);    // 0..63
  const int bx = local >> 3;               // 0..63
  const int row0 = by * 128;
  const int col0 = bx * 128;

  // staging: panel = 16 KB. tid covers panel-pair u2=tid>>7, record
  // sp=(tid>>6)&1, inner (tid&63)*16 -> LDS byte tid*16 (pure linear).
  const int u2 = tid >> 7;
  const int sp_ = (tid >> 6) & 1;
  const int inner = (tid & 63) * 16;
  const unsigned char* gA =
      A + ((size_t)(by * 4 + u2)) * 16384 + sp_ * 1024 + inner;
  const unsigned char* gB =
      B + ((size_t)(bx * 4 + u2)) * 16384 + sp_ * 1024 + inner;

  f32x16 acc[2][2] = {};

// stage K-tile kt (2 records/panel = 2048 B global stride per kt)
#define STAGE(kt)                                                        \
  do {                                                                   \
    async16(gA + (size_t)(kt)*2048, &sA[tid * 16]);                      \
    async16(gA + 2 * 16384 + (size_t)(kt)*2048, &sA[4096 + tid * 16]);   \
    async16(gB + (size_t)(kt)*2048, &sB[tid * 16]);                      \
    async16(gB + 2 * 16384 + (size_t)(kt)*2048, &sB[4096 + tid * 16]);   \
  } while (0)

// fp4 fragment: ONE b128 (16 B = 32 fp4), upper operand regs zero
#define LD16(dst, base, off)                                        \
  do {                                                              \
    frag32 _f;                                                      \
    _f.s.lo = *(const i32x4*)((base) + (off));                      \
    _f.s.hi = (i32x4){0, 0, 0, 0};                                  \
    dst = _f.v8;                                                    \
  } while (0)

#define MFMA(ci, a_, b_)                                            \
  ci = __builtin_amdgcn_mfma_scale_f32_32x32x64_f8f6f4(             \
      a_, b_, ci, 4, 4, 0, UNIT_SCALE, 0, UNIT_SCALE)

  const int lofs = lane * 16;
  const int aoff0 = (wm * 2 + 0) * 2048 + lofs;  // + sp*1024
  const int aoff1 = (wm * 2 + 1) * 2048 + lofs;
  const int boff0 = (wn * 2 + 0) * 2048 + lofs;
  const int boff1 = (wn * 2 + 1) * 2048 + lofs;

#pragma unroll 1
  for (int kt = 0; kt < 8; ++kt) {
    STAGE(kt);
    __syncthreads();  // tile resident
#pragma unroll
    for (int sp = 0; sp < 2; ++sp) {
      i32x8 a0, a1, b0, b1;
      LD16(a0, sA, aoff0 + sp * 1024);
      LD16(a1, sA, aoff1 + sp * 1024);
      LD16(b0, sB, boff0 + sp * 1024);
      LD16(b1, sB, boff1 + sp * 1024);
      MFMA(acc[0][0], a0, b0);
      MFMA(acc[0][1], a0, b1);
      MFMA(acc[1][0], a1, b0);
      MFMA(acc[1][1], a1, b1);
    }
    __syncthreads();  // reads done before next STAGE overwrites
  }

  // ---- epilogue: 32x32 C/D layout col=lane&31,
  //      row=(reg&3)+8*(reg>>2)+4*(lane>>5)  (shape-determined,
  //      dtype-independent per guide; verified absmax 0 at fp8)
  const int l31 = lane & 31;
  const int hi = lane >> 5;
  const int lb0 = lb[col0 + wn * 64 + l31];
  const int lb1 = lb[col0 + wn * 64 + 32 + l31];
  const int rbase = row0 + wm * 64 + 4 * hi;

#pragma unroll
  for (int mi = 0; mi < 2; mi++) {
#pragma unroll
    for (int r = 0; r < 16; r++) {
      const int row = rbase + mi * 32 + (r & 3) + 8 * (r >> 2);
      const int lav = la[row];
      float s0 = acc[mi][0][r] * SCALE_EPI;
      float s1 = acc[mi][1][r] * SCALE_EPI;
      s0 = fminf(fmaxf(s0, -50.f), 50.f);
      s1 = fminf(fmaxf(s1, -50.f), 50.f);
      const float e0 = __expf(s0);
      const float e1 = __expf(s1);
      float sneg = e0 + e1;
      float spos = (lav == lb0 ? e0 : 0.f) + (lav == lb1 ? e1 : 0.f);
#pragma unroll
      for (int m = 16; m >= 1; m >>= 1) {
        sneg += __shfl_xor(sneg, m, 32);
        spos += __shfl_xor(spos, m, 32);
      }
      if (l31 == 0) {
        atomicAdd(&neg_acc[row], sneg);
        atomicAdd(&pos_acc[row], spos);
      }
    }
  }
}

// ============================================================
// Kernel 3: loss = mean( log(neg) - log(max(pos,1e-8)) ) (unchanged)
// ============================================================
__global__ __launch_bounds__(1024) void final_reduce(
    const float* __restrict__ pos, const float* __restrict__ neg,
    float* __restrict__ out, int N) {
  double local = 0.0;
  const int t = threadIdx.x;
  for (int i = t; i < N / 4; i += 1024) {
    const float4 p4 = ((const float4*)pos)[i];
    const float4 n4 = ((const float4*)neg)[i];
    local += (double)(logf(n4.x) - logf(fmaxf(p4.x, 1e-8f)));
    local += (double)(logf(n4.y) - logf(fmaxf(p4.y, 1e-8f)));
    local += (double)(logf(n4.z) - logf(fmaxf(p4.z, 1e-8f)));
    local += (double)(logf(n4.w) - logf(fmaxf(p4.w, 1e-8f)));
  }
#pragma unroll
  for (int m = 32; m >= 1; m >>= 1) local += __shfl_xor(local, m, 64);
  __shared__ double wsum[16];
  const int wave = t >> 6, lane = t & 63;
  if (lane == 0) wsum[wave] = local;
  __syncthreads();
  if (t == 0) {
    double tot = 0.0;
#pragma unroll
    for (int w = 0; w < 16; w++) tot += wsum[w];
    out[0] = (float)(tot / (double)N);
  }
}

extern "C" void kernel_launch(void* const* d_in, const int* in_sizes, int n_in,
                              void* d_out, int out_size, void* d_ws, size_t ws_size,
                              hipStream_t stream) {
  const float* fa = (const float*)d_in[0];
  const float* fb = (const float*)d_in[1];
  const int* la = (const int*)d_in[2];
  const int* lb = (const int*)d_in[3];

  const int D = 1024;
  const int N = in_sizes[0] / D;  // 8192
  const int M = in_sizes[1] / D;  // 8192

  unsigned char* nA = (unsigned char*)d_ws;            // 4 MB fp4
  unsigned char* nB = nA + (size_t)N * D / 2;          // 4 MB fp4
  float* pos = (float*)(nB + (size_t)M * D / 2);
  float* neg = pos + N;

  normalize_rows<<<512, 1024, 0, stream>>>(fa, fb, (int*)nA, (int*)nB, pos,
                                           neg, N, D);

  infonce_gemm<<<4096, 256, 0, stream>>>(nA, nB, la, lb, pos, neg);

  final_reduce<<<1, 1024, 0, stream>>>(pos, neg, (float*)d_out, N);
}

// Round 9
// 208.819 us; speedup vs baseline: 4.0702x; 4.0702x over previous
//
#include <hip/hip_runtime.h>
#include <hip/hip_bf16.h>
#include <math.h>

typedef __attribute__((ext_vector_type(4))) float f32x4;
typedef __attribute__((ext_vector_type(16))) float f32x16;
typedef __attribute__((ext_vector_type(8))) int i32x8;
typedef __attribute__((ext_vector_type(4))) int i32x4;

#define TEMP_INV 14.2857142857142857f     // 1/0.07
#define SCALE_EPI 0.013950892857142857f   // TEMP_INV / 1024 (32*32 prescale)
#define UNIT_SCALE 0x7f7f7f7f             // E8M0 127 -> x1.0 exact (verified)

union frag32 {
  i32x8 v8;
  struct { i32x4 lo; i32x4 hi; } s;
};

// ---- async global->LDS, 16B per lane
static __device__ inline void async16(const void* g, void* l) {
  __builtin_amdgcn_global_load_lds(
      (const __attribute__((address_space(1))) unsigned int*)g,
      (__attribute__((address_space(3))) unsigned int*)l,
      16, 0, 0);
}

// ---- OCP fp4 e2m1 encode of y (|y| clamped to 6): monotone 3-bit code
// values {0,0.5,1,1.5,2,3,4,6}; round-to-nearest via threshold counts.
static __device__ inline int fp4e(float y) {
  const float af = fabsf(y);
  int code = (af > 0.25f) + (af > 0.75f) + (af > 1.25f) + (af > 1.75f) +
             (af > 2.5f) + (af > 3.5f) + (af > 5.0f);
  return code | (y < 0.f ? 8 : 0);
}

// ============================================================
// Fragment-major MX-fp4 format (verified R8: absmax 0.031, passes):
//   panel p = 32 rows, k-step s = 64 K-elems. record(p,s) = 1 KB at
//   (p*16+s)*1024. Lane l holds row p*32+(l&31), k-elems
//   s*64+(l>>5)*32..+31 as 16 B at rec + l*16. Values are 32*x
//   (exact pow-2 prescale); epilogue folds /1024 into SCALE_EPI.
// ============================================================

// ============================================================
// Kernel 1: L2-normalize rows (D=1024) -> fp4 fragment-major.
// (unchanged from R8 — verified correct)
// ============================================================
__global__ __launch_bounds__(1024) void normalize_rows(
    const float* __restrict__ a, const float* __restrict__ b,
    int* __restrict__ oa, int* __restrict__ ob,
    float* __restrict__ pos_acc, float* __restrict__ neg_acc,
    int N, int D) {
  __shared__ __align__(16) unsigned short sPk[8192];  // 16 KB

  const int blk = blockIdx.x;          // 0..511
  const bool isA = blk < 256;
  const int p = isA ? blk : blk - 256;
  const float* src = (isA ? a : b) + (size_t)p * 32 * D;
  int* out = isA ? oa : ob;

  const int tid = threadIdx.x;
  const int r = tid >> 5;   // row within panel
  const int c = tid & 31;   // chunk within row

  if (isA && c == 0) {
    pos_acc[p * 32 + r] = 0.f;
    neg_acc[p * 32 + r] = 0.f;
  }

  const float4* inr = (const float4*)(src + (size_t)r * D);
  float4 v[8];
#pragma unroll
  for (int i = 0; i < 8; i++) v[i] = inr[c + 32 * i];

  float ss = 0.f;
#pragma unroll
  for (int i = 0; i < 8; i++)
    ss += v[i].x * v[i].x + v[i].y * v[i].y + v[i].z * v[i].z + v[i].w * v[i].w;
#pragma unroll
  for (int m = 16; m >= 1; m >>= 1) ss += __shfl_xor(ss, m, 32);
  const float inv = 32.0f / fmaxf(sqrtf(ss), 1e-12f);  // pre-scale by 32

#pragma unroll
  for (int i = 0; i < 8; i++) {
    const int f = c + 32 * i;  // float4 index; k-base = 4f
    const int n0 = fp4e(v[i].x * inv);
    const int n1 = fp4e(v[i].y * inv);
    const int n2 = fp4e(v[i].z * inv);
    const int n3 = fp4e(v[i].w * inv);
    const unsigned short h =
        (unsigned short)(n0 | (n1 << 4) | (n2 << 8) | (n3 << 12));
    const int s = f >> 4;            // 64-k step
    const int hi = (f >> 3) & 1;     // k-half -> lane group
    sPk[s * 512 + (hi * 32 + r) * 8 + (f & 7)] = h;
  }
  __syncthreads();

  // linear copy-out: 16 KB = 1024 int4, one per thread
  const int4* sp4 = (const int4*)sPk;
  ((int4*)out)[(size_t)p * 1024 + tid] = sp4[tid];
}

// ============================================================
// Kernel 2: fused MX-fp4 MFMA GEMM + exp epilogue.
// R9 = R8 with ONE change: __launch_bounds__(256,6) -> (256,4).
// R8 post-mortem: the per-SIMD unified reg pool is ~512 (m69: waves
// halve at 64/128/256), so (256,6) capped waves at 85 regs -> acc
// (64 AGPR) could not be allocated -> per-iter scratch spill
// (WRITE 2.13 GB, 788 us). At (256,4): budget 128, need ~120
// (64 acc + ~56 VGPR, R5-measured), R0 precedent closes at exactly
// this budget with 4 blocks/CU (the proven best overlap regime).
// Everything else byte-identical to R8 (fp4 verified: absmax 0.031).
// ============================================================
__global__ __launch_bounds__(256, 4) void infonce_gemm(
    const unsigned char* __restrict__ A, const unsigned char* __restrict__ B,
    const int* __restrict__ la, const int* __restrict__ lb,
    float* __restrict__ pos_acc, float* __restrict__ neg_acc) {
  __shared__ __align__(16) unsigned char sA[8192];
  __shared__ __align__(16) unsigned char sB[8192];

  const int tid = threadIdx.x;
  const int lane = tid & 63;
  const int wave = tid >> 6;  // 0..3
  const int wm = wave >> 1;   // 0..1 (M half: 64 rows)
  const int wn = wave & 1;    // 0..1 (N half: 64 cols)

  // grid 4096 = 64 by x 64 bx; bijective XCD rectangle swizzle
  const int bid = blockIdx.x;
  const int xcd = bid & 7;
  const int local = bid >> 3;              // 0..511
  const int by = xcd * 8 + (local & 7);    // 0..63
  const int bx = local >> 3;               // 0..63
  const int row0 = by * 128;
  const int col0 = bx * 128;

  // staging: panel = 16 KB. tid covers panel-pair u2=tid>>7, record
  // sp=(tid>>6)&1, inner (tid&63)*16 -> LDS byte tid*16 (pure linear).
  const int u2 = tid >> 7;
  const int sp_ = (tid >> 6) & 1;
  const int inner = (tid & 63) * 16;
  const unsigned char* gA =
      A + ((size_t)(by * 4 + u2)) * 16384 + sp_ * 1024 + inner;
  const unsigned char* gB =
      B + ((size_t)(bx * 4 + u2)) * 16384 + sp_ * 1024 + inner;

  f32x16 acc[2][2] = {};

// stage K-tile kt (2 records/panel = 2048 B global stride per kt)
#define STAGE(kt)                                                        \
  do {                                                                   \
    async16(gA + (size_t)(kt)*2048, &sA[tid * 16]);                      \
    async16(gA + 2 * 16384 + (size_t)(kt)*2048, &sA[4096 + tid * 16]);   \
    async16(gB + (size_t)(kt)*2048, &sB[tid * 16]);                      \
    async16(gB + 2 * 16384 + (size_t)(kt)*2048, &sB[4096 + tid * 16]);   \
  } while (0)

// fp4 fragment: ONE b128 (16 B = 32 fp4), upper operand regs zero
#define LD16(dst, base, off)                                        \
  do {                                                              \
    frag32 _f;                                                      \
    _f.s.lo = *(const i32x4*)((base) + (off));                      \
    _f.s.hi = (i32x4){0, 0, 0, 0};                                  \
    dst = _f.v8;                                                    \
  } while (0)

#define MFMA(ci, a_, b_)                                            \
  ci = __builtin_amdgcn_mfma_scale_f32_32x32x64_f8f6f4(             \
      a_, b_, ci, 4, 4, 0, UNIT_SCALE, 0, UNIT_SCALE)

  const int lofs = lane * 16;
  const int aoff0 = (wm * 2 + 0) * 2048 + lofs;  // + sp*1024
  const int aoff1 = (wm * 2 + 1) * 2048 + lofs;
  const int boff0 = (wn * 2 + 0) * 2048 + lofs;
  const int boff1 = (wn * 2 + 1) * 2048 + lofs;

#pragma unroll 1
  for (int kt = 0; kt < 8; ++kt) {
    STAGE(kt);
    __syncthreads();  // tile resident
#pragma unroll
    for (int sp = 0; sp < 2; ++sp) {
      i32x8 a0, a1, b0, b1;
      LD16(a0, sA, aoff0 + sp * 1024);
      LD16(a1, sA, aoff1 + sp * 1024);
      LD16(b0, sB, boff0 + sp * 1024);
      LD16(b1, sB, boff1 + sp * 1024);
      MFMA(acc[0][0], a0, b0);
      MFMA(acc[0][1], a0, b1);
      MFMA(acc[1][0], a1, b0);
      MFMA(acc[1][1], a1, b1);
    }
    __syncthreads();  // reads done before next STAGE overwrites
  }

  // ---- epilogue: 32x32 C/D layout col=lane&31,
  //      row=(reg&3)+8*(reg>>2)+4*(lane>>5)  (shape-determined,
  //      dtype-independent; verified absmax 0 at fp8, 0.031 at fp4)
  const int l31 = lane & 31;
  const int hi = lane >> 5;
  const int lb0 = lb[col0 + wn * 64 + l31];
  const int lb1 = lb[col0 + wn * 64 + 32 + l31];
  const int rbase = row0 + wm * 64 + 4 * hi;

#pragma unroll
  for (int mi = 0; mi < 2; mi++) {
#pragma unroll
    for (int r = 0; r < 16; r++) {
      const int row = rbase + mi * 32 + (r & 3) + 8 * (r >> 2);
      const int lav = la[row];
      float s0 = acc[mi][0][r] * SCALE_EPI;
      float s1 = acc[mi][1][r] * SCALE_EPI;
      s0 = fminf(fmaxf(s0, -50.f), 50.f);
      s1 = fminf(fmaxf(s1, -50.f), 50.f);
      const float e0 = __expf(s0);
      const float e1 = __expf(s1);
      float sneg = e0 + e1;
      float spos = (lav == lb0 ? e0 : 0.f) + (lav == lb1 ? e1 : 0.f);
#pragma unroll
      for (int m = 16; m >= 1; m >>= 1) {
        sneg += __shfl_xor(sneg, m, 32);
        spos += __shfl_xor(spos, m, 32);
      }
      if (l31 == 0) {
        atomicAdd(&neg_acc[row], sneg);
        atomicAdd(&pos_acc[row], spos);
      }
    }
  }
}

// ============================================================
// Kernel 3: loss = mean( log(neg) - log(max(pos,1e-8)) ) (unchanged)
// ============================================================
__global__ __launch_bounds__(1024) void final_reduce(
    const float* __restrict__ pos, const float* __restrict__ neg,
    float* __restrict__ out, int N) {
  double local = 0.0;
  const int t = threadIdx.x;
  for (int i = t; i < N / 4; i += 1024) {
    const float4 p4 = ((const float4*)pos)[i];
    const float4 n4 = ((const float4*)neg)[i];
    local += (double)(logf(n4.x) - logf(fmaxf(p4.x, 1e-8f)));
    local += (double)(logf(n4.y) - logf(fmaxf(p4.y, 1e-8f)));
    local += (double)(logf(n4.z) - logf(fmaxf(p4.z, 1e-8f)));
    local += (double)(logf(n4.w) - logf(fmaxf(p4.w, 1e-8f)));
  }
#pragma unroll
  for (int m = 32; m >= 1; m >>= 1) local += __shfl_xor(local, m, 64);
  __shared__ double wsum[16];
  const int wave = t >> 6, lane = t & 63;
  if (lane == 0) wsum[wave] = local;
  __syncthreads();
  if (t == 0) {
    double tot = 0.0;
#pragma unroll
    for (int w = 0; w < 16; w++) tot += wsum[w];
    out[0] = (float)(tot / (double)N);
  }
}

extern "C" void kernel_launch(void* const* d_in, const int* in_sizes, int n_in,
                              void* d_out, int out_size, void* d_ws, size_t ws_size,
                              hipStream_t stream) {
  const float* fa = (const float*)d_in[0];
  const float* fb = (const float*)d_in[1];
  const int* la = (const int*)d_in[2];
  const int* lb = (const int*)d_in[3];

  const int D = 1024;
  const int N = in_sizes[0] / D;  // 8192
  const int M = in_sizes[1] / D;  // 8192

  unsigned char* nA = (unsigned char*)d_ws;            // 4 MB fp4
  unsigned char* nB = nA + (size_t)N * D / 2;          // 4 MB fp4
  float* pos = (float*)(nB + (size_t)M * D / 2);
  float* neg = pos + N;

  normalize_rows<<<512, 1024, 0, stream>>>(fa, fb, (int*)nA, (int*)nB, pos,
                                           neg, N, D);

  infonce_gemm<<<4096, 256, 0, stream>>>(nA, nB, la, lb, pos, neg);

  final_reduce<<<1, 1024, 0, stream>>>(pos, neg, (float*)d_out, N);
}

// Round 10
// 155.625 us; speedup vs baseline: 5.4615x; 1.3418x over previous
//
#include <hip/hip_runtime.h>
#include <hip/hip_bf16.h>
#include <math.h>

typedef __attribute__((ext_vector_type(4))) float f32x4;
typedef __attribute__((ext_vector_type(16))) float f32x16;
typedef __attribute__((ext_vector_type(8))) int i32x8;
typedef __attribute__((ext_vector_type(4))) int i32x4;

#define TEMP_INV 14.2857142857142857f     // 1/0.07
#define SCALE_EPI 0.013950892857142857f   // TEMP_INV / 1024 (32*32 prescale)
#define UNIT_SCALE 0x7f7f7f7f             // E8M0 127 -> x1.0 exact (verified)

union frag32 {
  i32x8 v8;
  struct { i32x4 lo; i32x4 hi; } s;
};

// ---- async global->LDS, 16B per lane
static __device__ inline void async16(const void* g, void* l) {
  __builtin_amdgcn_global_load_lds(
      (const __attribute__((address_space(1))) unsigned int*)g,
      (__attribute__((address_space(3))) unsigned int*)l,
      16, 0, 0);
}

// ---- OCP fp4 e2m1 encode of y (|y| clamped to 6): monotone 3-bit code
static __device__ inline int fp4e(float y) {
  const float af = fabsf(y);
  int code = (af > 0.25f) + (af > 0.75f) + (af > 1.25f) + (af > 1.75f) +
             (af > 2.5f) + (af > 3.5f) + (af > 5.0f);
  return code | (y < 0.f ? 8 : 0);
}

// ============================================================
// Fragment-major MX-fp4 format (verified R8/R9: absmax 0.031, passes):
//   panel p = 32 rows, k-step s = 64 K-elems. record(p,s) = 1 KB at
//   (p*16+s)*1024. Lane l holds row p*32+(l&31), k-elems
//   s*64+(l>>5)*32..+31 as 16 B at rec + l*16. Values are 32*x.
// ============================================================

// ============================================================
// Kernel 1: L2-normalize rows (D=1024) -> fp4 fragment-major.
// (unchanged from R8/R9 — verified correct)
// ============================================================
__global__ __launch_bounds__(1024) void normalize_rows(
    const float* __restrict__ a, const float* __restrict__ b,
    int* __restrict__ oa, int* __restrict__ ob,
    float* __restrict__ pos_acc, float* __restrict__ neg_acc,
    int N, int D) {
  __shared__ __align__(16) unsigned short sPk[8192];  // 16 KB

  const int blk = blockIdx.x;          // 0..511
  const bool isA = blk < 256;
  const int p = isA ? blk : blk - 256;
  const float* src = (isA ? a : b) + (size_t)p * 32 * D;
  int* out = isA ? oa : ob;

  const int tid = threadIdx.x;
  const int r = tid >> 5;   // row within panel
  const int c = tid & 31;   // chunk within row

  if (isA && c == 0) {
    pos_acc[p * 32 + r] = 0.f;
    neg_acc[p * 32 + r] = 0.f;
  }

  const float4* inr = (const float4*)(src + (size_t)r * D);
  float4 v[8];
#pragma unroll
  for (int i = 0; i < 8; i++) v[i] = inr[c + 32 * i];

  float ss = 0.f;
#pragma unroll
  for (int i = 0; i < 8; i++)
    ss += v[i].x * v[i].x + v[i].y * v[i].y + v[i].z * v[i].z + v[i].w * v[i].w;
#pragma unroll
  for (int m = 16; m >= 1; m >>= 1) ss += __shfl_xor(ss, m, 32);
  const float inv = 32.0f / fmaxf(sqrtf(ss), 1e-12f);  // pre-scale by 32

#pragma unroll
  for (int i = 0; i < 8; i++) {
    const int f = c + 32 * i;  // float4 index; k-base = 4f
    const int n0 = fp4e(v[i].x * inv);
    const int n1 = fp4e(v[i].y * inv);
    const int n2 = fp4e(v[i].z * inv);
    const int n3 = fp4e(v[i].w * inv);
    const unsigned short h =
        (unsigned short)(n0 | (n1 << 4) | (n2 << 8) | (n3 << 12));
    const int s = f >> 4;            // 64-k step
    const int hi = (f >> 3) & 1;     // k-half -> lane group
    sPk[s * 512 + (hi * 32 + r) * 8 + (f & 7)] = h;
  }
  __syncthreads();

  const int4* sp4 = (const int4*)sPk;
  ((int4*)out)[(size_t)p * 1024 + tid] = sp4[tid];
}

// ============================================================
// Kernel 2: fused MX-fp4 MFMA GEMM + exp epilogue.
// R10 = R9 envelope ((256,4), 4 blocks/CU, no loop asm) with:
//  * BK=256: 4 K-iters (was 8) -> halves barrier/drain events.
//    LDS 2x16 KB = 32 KB, x4 blocks = 128 <= 160 KB.
//  * Epilogue overhaul: clamps dropped (|s|<=~16<50: no-op in ref
//    AND kernel); halving-butterfly row reduce (64 shuffles/wave vs
//    320); atomics from 32 lanes to distinct rows (no serial tail).
//    mi-chunked to bound peak regs (~110 <= 128 budget).
// ============================================================
__global__ __launch_bounds__(256, 4) void infonce_gemm(
    const unsigned char* __restrict__ A, const unsigned char* __restrict__ B,
    const int* __restrict__ la, const int* __restrict__ lb,
    float* __restrict__ pos_acc, float* __restrict__ neg_acc) {
  __shared__ __align__(16) unsigned char sA[16384];
  __shared__ __align__(16) unsigned char sB[16384];

  const int tid = threadIdx.x;
  const int lane = tid & 63;
  const int wave = tid >> 6;  // 0..3
  const int wm = wave >> 1;   // 0..1 (M half: 64 rows)
  const int wn = wave & 1;    // 0..1 (N half: 64 cols)

  // grid 4096 = 64 by x 64 bx; bijective XCD rectangle swizzle
  const int bid = blockIdx.x;
  const int xcd = bid & 7;
  const int local = bid >> 3;              // 0..511
  const int by = xcd * 8 + (local & 7);    // 0..63
  const int bx = local >> 3;               // 0..63
  const int row0 = by * 128;
  const int col0 = bx * 128;

  // staging: 4 panels x 4 records per iter. tid covers record
  // sr=(tid>>6)&3, inner (tid&63)*16; panel u unrolled.
  const unsigned char* gA =
      A + (size_t)by * 65536 + ((tid >> 6) & 3) * 1024 + (tid & 63) * 16;
  const unsigned char* gB =
      B + (size_t)bx * 65536 + ((tid >> 6) & 3) * 1024 + (tid & 63) * 16;

  f32x16 acc[2][2] = {};

// stage K-tile kt (4 records/panel = 4096 B global stride per kt)
#define STAGE(kt)                                                   \
  do {                                                              \
    _Pragma("unroll") for (int u = 0; u < 4; u++) {                 \
      async16(gA + (size_t)u * 16384 + (size_t)(kt)*4096,           \
              &sA[u * 4096 + tid * 16]);                            \
      async16(gB + (size_t)u * 16384 + (size_t)(kt)*4096,           \
              &sB[u * 4096 + tid * 16]);                            \
    }                                                               \
  } while (0)

// fp4 fragment: ONE b128 (16 B = 32 fp4), upper operand regs zero
#define LD16(dst, base, off)                                        \
  do {                                                              \
    frag32 _f;                                                      \
    _f.s.lo = *(const i32x4*)((base) + (off));                      \
    _f.s.hi = (i32x4){0, 0, 0, 0};                                  \
    dst = _f.v8;                                                    \
  } while (0)

#define MFMA(ci, a_, b_)                                            \
  ci = __builtin_amdgcn_mfma_scale_f32_32x32x64_f8f6f4(             \
      a_, b_, ci, 4, 4, 0, UNIT_SCALE, 0, UNIT_SCALE)

  const int lofs = lane * 16;
  const int aoff0 = (wm * 2 + 0) * 4096 + lofs;  // + sp*1024
  const int aoff1 = (wm * 2 + 1) * 4096 + lofs;
  const int boff0 = (wn * 2 + 0) * 4096 + lofs;
  const int boff1 = (wn * 2 + 1) * 4096 + lofs;

#pragma unroll 1
  for (int kt = 0; kt < 4; ++kt) {
    STAGE(kt);
    __syncthreads();  // tile resident
#pragma unroll
    for (int sp = 0; sp < 4; ++sp) {
      i32x8 fa0, fa1, fb0, fb1;
      LD16(fa0, sA, aoff0 + sp * 1024);
      LD16(fa1, sA, aoff1 + sp * 1024);
      LD16(fb0, sB, boff0 + sp * 1024);
      LD16(fb1, sB, boff1 + sp * 1024);
      MFMA(acc[0][0], fa0, fb0);
      MFMA(acc[0][1], fa0, fb1);
      MFMA(acc[1][0], fa1, fb0);
      MFMA(acc[1][1], fa1, fb1);
    }
    __syncthreads();  // reads done before next STAGE overwrites
  }

  // ---- epilogue. C/D 32x32 layout: col=lane&31,
  //      row=(reg&3)+8*(reg>>2)+4*(lane>>5)  (verified).
  // Halving butterfly: after masks 1,2,4,8 lane l31 holds the 16-lane
  // group partial for r = l31&15; flat mask-16 add completes the
  // 32-column sum (duplicated l31 <-> l31^16); lanes l31<16 commit.
  const int l31 = lane & 31;
  const int hi = lane >> 5;
  const int lb0 = lb[col0 + wn * 64 + l31];
  const int lb1 = lb[col0 + wn * 64 + 32 + l31];
  const int rbase = row0 + wm * 64 + 4 * hi;
  const int rfin = rbase + (l31 & 3) + 8 * ((l31 >> 2) & 3);
  const int bb0 = l31 & 1, bb1 = (l31 >> 1) & 1, bb2 = (l31 >> 2) & 1,
            bb3 = (l31 >> 3) & 1;

#pragma unroll
  for (int mi = 0; mi < 2; mi++) {
    float vn[16], vp[16];
#pragma unroll
    for (int r = 0; r < 16; r++) {
      const int row = rbase + mi * 32 + (r & 3) + 8 * (r >> 2);
      const int lav = la[row];
      const float e0 = __expf(acc[mi][0][r] * SCALE_EPI);  // no clamp: |s|<50
      const float e1 = __expf(acc[mi][1][r] * SCALE_EPI);
      vn[r] = e0 + e1;
      vp[r] = (lav == lb0 ? e0 : 0.f) + (lav == lb1 ? e1 : 0.f);
    }
    float an[8], ap[8];
#pragma unroll
    for (int t = 0; t < 8; t++) {
      float sn = bb0 ? vn[2 * t] : vn[2 * t + 1];
      float sp = bb0 ? vp[2 * t] : vp[2 * t + 1];
      float kn = bb0 ? vn[2 * t + 1] : vn[2 * t];
      float kp = bb0 ? vp[2 * t + 1] : vp[2 * t];
      an[t] = kn + __shfl_xor(sn, 1, 64);
      ap[t] = kp + __shfl_xor(sp, 1, 64);
    }
    float cn[4], cp[4];
#pragma unroll
    for (int t = 0; t < 4; t++) {
      float sn = bb1 ? an[2 * t] : an[2 * t + 1];
      float sp = bb1 ? ap[2 * t] : ap[2 * t + 1];
      float kn = bb1 ? an[2 * t + 1] : an[2 * t];
      float kp = bb1 ? ap[2 * t + 1] : ap[2 * t];
      cn[t] = kn + __shfl_xor(sn, 2, 64);
      cp[t] = kp + __shfl_xor(sp, 2, 64);
    }
    float dn[2], dp[2];
#pragma unroll
    for (int t = 0; t < 2; t++) {
      float sn = bb2 ? cn[2 * t] : cn[2 * t + 1];
      float sp = bb2 ? cp[2 * t] : cp[2 * t + 1];
      float kn = bb2 ? cn[2 * t + 1] : cn[2 * t];
      float kp = bb2 ? cp[2 * t + 1] : cp[2 * t];
      dn[t] = kn + __shfl_xor(sn, 4, 64);
      dp[t] = kp + __shfl_xor(sp, 4, 64);
    }
    float sn4 = bb3 ? dn[0] : dn[1];
    float sp4 = bb3 ? dp[0] : dp[1];
    float fn = (bb3 ? dn[1] : dn[0]) + __shfl_xor(sn4, 8, 64);
    float fp = (bb3 ? dp[1] : dp[0]) + __shfl_xor(sp4, 8, 64);
    fn += __shfl_xor(fn, 16, 64);
    fp += __shfl_xor(fp, 16, 64);
    if (l31 < 16) {
      const int row = rfin + mi * 32;
      atomicAdd(&neg_acc[row], fn);
      atomicAdd(&pos_acc[row], fp);
    }
  }
}

// ============================================================
// Kernel 3: loss = mean( log(neg) - log(max(pos,1e-8)) ) (unchanged)
// ============================================================
__global__ __launch_bounds__(1024) void final_reduce(
    const float* __restrict__ pos, const float* __restrict__ neg,
    float* __restrict__ out, int N) {
  double local = 0.0;
  const int t = threadIdx.x;
  for (int i = t; i < N / 4; i += 1024) {
    const float4 p4 = ((const float4*)pos)[i];
    const float4 n4 = ((const float4*)neg)[i];
    local += (double)(logf(n4.x) - logf(fmaxf(p4.x, 1e-8f)));
    local += (double)(logf(n4.y) - logf(fmaxf(p4.y, 1e-8f)));
    local += (double)(logf(n4.z) - logf(fmaxf(p4.z, 1e-8f)));
    local += (double)(logf(n4.w) - logf(fmaxf(p4.w, 1e-8f)));
  }
#pragma unroll
  for (int m = 32; m >= 1; m >>= 1) local += __shfl_xor(local, m, 64);
  __shared__ double wsum[16];
  const int wave = t >> 6, lane = t & 63;
  if (lane == 0) wsum[wave] = local;
  __syncthreads();
  if (t == 0) {
    double tot = 0.0;
#pragma unroll
    for (int w = 0; w < 16; w++) tot += wsum[w];
    out[0] = (float)(tot / (double)N);
  }
}

extern "C" void kernel_launch(void* const* d_in, const int* in_sizes, int n_in,
                              void* d_out, int out_size, void* d_ws, size_t ws_size,
                              hipStream_t stream) {
  const float* fa = (const float*)d_in[0];
  const float* fb = (const float*)d_in[1];
  const int* la = (const int*)d_in[2];
  const int* lb = (const int*)d_in[3];

  const int D = 1024;
  const int N = in_sizes[0] / D;  // 8192
  const int M = in_sizes[1] / D;  // 8192

  unsigned char* nA = (unsigned char*)d_ws;            // 4 MB fp4
  unsigned char* nB = nA + (size_t)N * D / 2;          // 4 MB fp4
  float* pos = (float*)(nB + (size_t)M * D / 2);
  float* neg = pos + N;

  normalize_rows<<<512, 1024, 0, stream>>>(fa, fb, (int*)nA, (int*)nB, pos,
                                           neg, N, D);

  infonce_gemm<<<4096, 256, 0, stream>>>(nA, nB, la, lb, pos, neg);

  final_reduce<<<1, 1024, 0, stream>>>(pos, neg, (float*)d_out, N);
}

// Round 11
// 148.093 us; speedup vs baseline: 5.7393x; 1.0509x over previous
//
#include <hip/hip_runtime.h>
#include <hip/hip_bf16.h>
#include <math.h>

typedef __attribute__((ext_vector_type(4))) float f32x4;
typedef __attribute__((ext_vector_type(16))) float f32x16;
typedef __attribute__((ext_vector_type(8))) int i32x8;
typedef __attribute__((ext_vector_type(4))) int i32x4;

#define TEMP_INV 14.2857142857142857f     // 1/0.07
#define SCALE_EPI 0.013950892857142857f   // TEMP_INV / 1024 (32*32 prescale)
#define UNIT_SCALE 0x7f7f7f7f             // E8M0 127 -> x1.0 exact (verified)

union frag32 {
  i32x8 v8;
  struct { i32x4 lo; i32x4 hi; } s;
};

// ---- async global->LDS, 16B per lane
static __device__ inline void async16(const void* g, void* l) {
  __builtin_amdgcn_global_load_lds(
      (const __attribute__((address_space(1))) unsigned int*)g,
      (__attribute__((address_space(3))) unsigned int*)l,
      16, 0, 0);
}

// ---- OCP fp4 e2m1 encode of y (|y| clamped to 6): monotone 3-bit code
static __device__ inline int fp4e(float y) {
  const float af = fabsf(y);
  int code = (af > 0.25f) + (af > 0.75f) + (af > 1.25f) + (af > 1.75f) +
             (af > 2.5f) + (af > 3.5f) + (af > 5.0f);
  return code | (y < 0.f ? 8 : 0);
}

// ============================================================
// Fragment-major MX-fp4 format (verified R8-R10: absmax 0.031):
//   panel p = 32 rows, k-step s = 64 K-elems. record(p,s) = 1 KB at
//   (p*16+s)*1024. Lane l holds row p*32+(l&31), k-elems
//   s*64+(l>>5)*32..+31 as 16 B at rec + l*16. Values are 32*x.
// ============================================================

// ============================================================
// Kernel 1: L2-normalize rows (D=1024) -> fp4 fragment-major.
// (R8-R10 verified; + zeroes out[0] for the atomic final reduce)
// ============================================================
__global__ __launch_bounds__(1024) void normalize_rows(
    const float* __restrict__ a, const float* __restrict__ b,
    int* __restrict__ oa, int* __restrict__ ob,
    float* __restrict__ pos_acc, float* __restrict__ neg_acc,
    float* __restrict__ dout, int N, int D) {
  __shared__ __align__(16) unsigned short sPk[8192];  // 16 KB

  const int blk = blockIdx.x;          // 0..511
  const bool isA = blk < 256;
  const int p = isA ? blk : blk - 256;
  const float* src = (isA ? a : b) + (size_t)p * 32 * D;
  int* out = isA ? oa : ob;

  const int tid = threadIdx.x;
  const int r = tid >> 5;   // row within panel
  const int c = tid & 31;   // chunk within row

  if (blk == 0 && tid == 0) dout[0] = 0.f;
  if (isA && c == 0) {
    pos_acc[p * 32 + r] = 0.f;
    neg_acc[p * 32 + r] = 0.f;
  }

  const float4* inr = (const float4*)(src + (size_t)r * D);
  float4 v[8];
#pragma unroll
  for (int i = 0; i < 8; i++) v[i] = inr[c + 32 * i];

  float ss = 0.f;
#pragma unroll
  for (int i = 0; i < 8; i++)
    ss += v[i].x * v[i].x + v[i].y * v[i].y + v[i].z * v[i].z + v[i].w * v[i].w;
#pragma unroll
  for (int m = 16; m >= 1; m >>= 1) ss += __shfl_xor(ss, m, 32);
  const float inv = 32.0f / fmaxf(sqrtf(ss), 1e-12f);  // pre-scale by 32

#pragma unroll
  for (int i = 0; i < 8; i++) {
    const int f = c + 32 * i;  // float4 index; k-base = 4f
    const int n0 = fp4e(v[i].x * inv);
    const int n1 = fp4e(v[i].y * inv);
    const int n2 = fp4e(v[i].z * inv);
    const int n3 = fp4e(v[i].w * inv);
    const unsigned short h =
        (unsigned short)(n0 | (n1 << 4) | (n2 << 8) | (n3 << 12));
    const int s = f >> 4;            // 64-k step
    const int hi = (f >> 3) & 1;     // k-half -> lane group
    sPk[s * 512 + (hi * 32 + r) * 8 + (f & 7)] = h;
  }
  __syncthreads();

  const int4* sp4 = (const int4*)sPk;
  ((int4*)out)[(size_t)p * 1024 + tid] = sp4[tid];
}

// ============================================================
// Kernel 2: fused MX-fp4 MFMA GEMM + exp epilogue.
// R11 = R10 envelope ((256,4), BK=256, 4 blocks/CU) with the MFMA
// OPERANDS SWAPPED: MFMA(acc, bfrag, afrag). By the verified C/D
// mapping (lane&31 indexes the 2nd operand's row), the lane now
// carries the A-ROW and the reg-pattern carries the B-COL, so the
// per-row column-sum is LANE-LOCAL: 32 reg adds + ONE xor-32 shuffle
// per array (4 shuffles total vs 64 + selects in R10). B-labels via
// 32 half-wave-uniform loads (L1 broadcast); A-labels 2 coalesced.
// Regs: acc 64 + lbs 32 + temps ~16 <= 128 budget (no spill).
// ============================================================
__global__ __launch_bounds__(256, 4) void infonce_gemm(
    const unsigned char* __restrict__ A, const unsigned char* __restrict__ B,
    const int* __restrict__ la, const int* __restrict__ lb,
    float* __restrict__ pos_acc, float* __restrict__ neg_acc) {
  __shared__ __align__(16) unsigned char sA[16384];
  __shared__ __align__(16) unsigned char sB[16384];

  const int tid = threadIdx.x;
  const int lane = tid & 63;
  const int wave = tid >> 6;  // 0..3
  const int wa = wave >> 1;   // 0..1 (A half: 64 rows)
  const int wb = wave & 1;    // 0..1 (B half: 64 cols)

  // grid 4096 = 64 by x 64 bx; bijective XCD rectangle swizzle
  const int bid = blockIdx.x;
  const int xcd = bid & 7;
  const int local = bid >> 3;              // 0..511
  const int by = xcd * 8 + (local & 7);    // 0..63
  const int bx = local >> 3;               // 0..63
  const int row0 = by * 128;
  const int col0 = bx * 128;

  // staging: 4 panels x 4 records per iter. tid covers record
  // sr=(tid>>6)&3, inner (tid&63)*16; panel u unrolled.
  const unsigned char* gA =
      A + (size_t)by * 65536 + ((tid >> 6) & 3) * 1024 + (tid & 63) * 16;
  const unsigned char* gB =
      B + (size_t)bx * 65536 + ((tid >> 6) & 3) * 1024 + (tid & 63) * 16;

  f32x16 acc[2][2] = {};  // [bi][aj]

#define STAGE(kt)                                                   \
  do {                                                              \
    _Pragma("unroll") for (int u = 0; u < 4; u++) {                 \
      async16(gA + (size_t)u * 16384 + (size_t)(kt)*4096,           \
              &sA[u * 4096 + tid * 16]);                            \
      async16(gB + (size_t)u * 16384 + (size_t)(kt)*4096,           \
              &sB[u * 4096 + tid * 16]);                            \
    }                                                               \
  } while (0)

// fp4 fragment: ONE b128 (16 B = 32 fp4), upper operand regs zero
#define LD16(dst, base, off)                                        \
  do {                                                              \
    frag32 _f;                                                      \
    _f.s.lo = *(const i32x4*)((base) + (off));                      \
    _f.s.hi = (i32x4){0, 0, 0, 0};                                  \
    dst = _f.v8;                                                    \
  } while (0)

#define MFMA(ci, x_, y_)                                            \
  ci = __builtin_amdgcn_mfma_scale_f32_32x32x64_f8f6f4(             \
      x_, y_, ci, 4, 4, 0, UNIT_SCALE, 0, UNIT_SCALE)

  const int lofs = lane * 16;
  const int aoff0 = (wa * 2 + 0) * 4096 + lofs;  // + sp*1024
  const int aoff1 = (wa * 2 + 1) * 4096 + lofs;
  const int boff0 = (wb * 2 + 0) * 4096 + lofs;
  const int boff1 = (wb * 2 + 1) * 4096 + lofs;

#pragma unroll 1
  for (int kt = 0; kt < 4; ++kt) {
    STAGE(kt);
    __syncthreads();  // tile resident
#pragma unroll
    for (int sp = 0; sp < 4; ++sp) {
      i32x8 fa0, fa1, fb0, fb1;
      LD16(fa0, sA, aoff0 + sp * 1024);
      LD16(fa1, sA, aoff1 + sp * 1024);
      LD16(fb0, sB, boff0 + sp * 1024);
      LD16(fb1, sB, boff1 + sp * 1024);
      // SWAPPED operand order: lane&31 <- A-row, regs <- B-col
      MFMA(acc[0][0], fb0, fa0);
      MFMA(acc[0][1], fb0, fa1);
      MFMA(acc[1][0], fb1, fa0);
      MFMA(acc[1][1], fb1, fa1);
    }
    __syncthreads();  // reads done before next STAGE overwrites
  }

  // ---- epilogue (swapped layout): acc[bi][aj][r], lane l31 = A-row
  //      aj*32+l31 (within wave's 64-row half), B-col = wb*64 + bi*32
  //      + (r&3)+8*(r>>2)+4*hi. Column-sum = lane-local over bi,r +
  //      one xor-32 exchange (hi halves are disjoint col sets).
  const int l31 = lane & 31;
  const int hi = lane >> 5;
  const int colw = col0 + wb * 64 + 4 * hi;
  const int rowbase = row0 + wa * 64 + l31;

  const int lav0 = la[rowbase];        // aj=0 row label
  const int lav1 = la[rowbase + 32];   // aj=1 row label

  // B labels at this lane's 32 column slots (half-wave-uniform addrs)
  int lbs[2][16];
#pragma unroll
  for (int bi = 0; bi < 2; bi++)
#pragma unroll
    for (int r = 0; r < 16; r++)
      lbs[bi][r] = lb[colw + bi * 32 + (r & 3) + 8 * (r >> 2)];

#pragma unroll
  for (int aj = 0; aj < 2; aj++) {
    const int lav = aj ? lav1 : lav0;
    float sn = 0.f, sp = 0.f;
#pragma unroll
    for (int bi = 0; bi < 2; bi++)
#pragma unroll
      for (int r = 0; r < 16; r++) {
        const float e = __expf(acc[bi][aj][r] * SCALE_EPI);  // |s|<50
        sn += e;
        sp += (lav == lbs[bi][r]) ? e : 0.f;
      }
    sn += __shfl_xor(sn, 32, 64);
    sp += __shfl_xor(sp, 32, 64);
    if (hi == 0) {
      const int row = rowbase + aj * 32;
      atomicAdd(&neg_acc[row], sn);
      atomicAdd(&pos_acc[row], sp);
    }
  }
}

// ============================================================
// Kernel 3: loss partials -> atomic mean. 8 blocks x 256 thr, one
// float4/thread (N/4 = 2048). out[0] zeroed by normalize (stream-
// ordered). Block partial via wave shuffle + LDS, one atomic/block.
// ============================================================
__global__ __launch_bounds__(256) void final_reduce(
    const float* __restrict__ pos, const float* __restrict__ neg,
    float* __restrict__ out, int N) {
  const int i = blockIdx.x * 256 + threadIdx.x;  // 0..2047
  const float4 p4 = ((const float4*)pos)[i];
  const float4 n4 = ((const float4*)neg)[i];
  float local = (logf(n4.x) - logf(fmaxf(p4.x, 1e-8f))) +
                (logf(n4.y) - logf(fmaxf(p4.y, 1e-8f))) +
                (logf(n4.z) - logf(fmaxf(p4.z, 1e-8f))) +
                (logf(n4.w) - logf(fmaxf(p4.w, 1e-8f)));
#pragma unroll
  for (int m = 32; m >= 1; m >>= 1) local += __shfl_xor(local, m, 64);
  __shared__ float ws[4];
  const int wv = threadIdx.x >> 6, lane = threadIdx.x & 63;
  if (lane == 0) ws[wv] = local;
  __syncthreads();
  if (threadIdx.x == 0)
    atomicAdd(out, (ws[0] + ws[1] + ws[2] + ws[3]) * (1.0f / (float)N));
}

extern "C" void kernel_launch(void* const* d_in, const int* in_sizes, int n_in,
                              void* d_out, int out_size, void* d_ws, size_t ws_size,
                              hipStream_t stream) {
  const float* fa = (const float*)d_in[0];
  const float* fb = (const float*)d_in[1];
  const int* la = (const int*)d_in[2];
  const int* lb = (const int*)d_in[3];

  const int D = 1024;
  const int N = in_sizes[0] / D;  // 8192
  const int M = in_sizes[1] / D;  // 8192

  unsigned char* nA = (unsigned char*)d_ws;            // 4 MB fp4
  unsigned char* nB = nA + (size_t)N * D / 2;          // 4 MB fp4
  float* pos = (float*)(nB + (size_t)M * D / 2);
  float* neg = pos + N;

  normalize_rows<<<512, 1024, 0, stream>>>(fa, fb, (int*)nA, (int*)nB, pos,
                                           neg, (float*)d_out, N, D);

  infonce_gemm<<<4096, 256, 0, stream>>>(nA, nB, la, lb, pos, neg);

  final_reduce<<<8, 256, 0, stream>>>(pos, neg, (float*)d_out, N);
}